// Round 7
// baseline (25.200 us; speedup 1.0000x reference)
//
#include <hip/hip_runtime.h>

// PoseLoss round 7: single-generation software-pipelined waves.
// Grid = 2048 one-wave blocks (8 resident/CU @ launch_bounds(64,2), LDS
// 16 KiB -> no turnover, no phase re-sync). Each wave owns 2 consecutive
// 256-sample chunks and issues ALL 50 dwordx4 loads up front (51 KB in
// flight/wave, ~410 KB/CU -> memory pipe never idles), pinned by
// sched_barrier(0). ds_write+compute chunk A drains only A's 25 loads
// (counted vmcnt); chunk B's loads land under A's compute. Single 16 KiB
// LDS buffer reused across chunks (same-wave DS ordering, no barrier).
// R5 lesson: no device-scope fences/atomics. R6 lesson: turnover order
// tweaks alone were neutral -> attack phase sync itself.

#define W1_XYZ 0.3f
#define W2_XYZ 0.3f
#define W3_XYZ 1.0f
#define W1_WPQR 150.0f
#define W2_WPQR 150.0f
#define W3_WPQR 500.0f

constexpr int B_TOTAL = 1048576;
constexpr int SPW     = 256;                       // samples per chunk
constexpr int CPW     = 2;                         // chunks per wave
constexpr int NBLOCKS = B_TOTAL / (SPW * CPW);     // 2048

__global__ __launch_bounds__(64, 2) void pose_loss_partial(
    const float* __restrict__ p1x, const float* __restrict__ p1q,
    const float* __restrict__ p2x, const float* __restrict__ p2q,
    const float* __restrict__ p3x, const float* __restrict__ p3q,
    const float* __restrict__ gt, float* __restrict__ partial)
{
    __shared__ __align__(16) float lds[4096];  // 16 KiB: x1,x2,x3 (768 f) + gt (1792 f)
    const int  lane = threadIdx.x;
    const long c0   = (long)blockIdx.x * CPW;
    const long c1   = c0 + 1;

    float* Lx1 = lds;
    float* Lx2 = lds + 768;
    float* Lx3 = lds + 1536;
    float* Lg  = lds + 2304;

    const float4* x1p = (const float4*)p1x;
    const float4* x2p = (const float4*)p2x;
    const float4* x3p = (const float4*)p3x;
    const float4* gp  = (const float4*)gt;
    const float4* q1p = (const float4*)p1q;
    const float4* q2p = (const float4*)p2q;
    const float4* q3p = (const float4*)p3q;

    // xs/gs first within each chunk (ds_write deps drain earliest), q last.
#define ISSUE(dx1, dx2, dx3, dg, dq1, dq2, dq3, c) do {                         \
    _Pragma("unroll") for (int j = 0; j < 3; ++j) dx1[j] = x1p[(c)*192 + j*64 + lane]; \
    _Pragma("unroll") for (int j = 0; j < 3; ++j) dx2[j] = x2p[(c)*192 + j*64 + lane]; \
    _Pragma("unroll") for (int j = 0; j < 3; ++j) dx3[j] = x3p[(c)*192 + j*64 + lane]; \
    _Pragma("unroll") for (int j = 0; j < 7; ++j) dg[j]  = gp [(c)*448 + j*64 + lane]; \
    _Pragma("unroll") for (int k = 0; k < 4; ++k) dq1[k] = q1p[(c)*256 + k*64 + lane]; \
    _Pragma("unroll") for (int k = 0; k < 4; ++k) dq2[k] = q2p[(c)*256 + k*64 + lane]; \
    _Pragma("unroll") for (int k = 0; k < 4; ++k) dq3[k] = q3p[(c)*256 + k*64 + lane]; \
  } while (0)

#define WRITE_LDS(sx1, sx2, sx3, sg) do {                                       \
    _Pragma("unroll") for (int j = 0; j < 3; ++j) ((float4*)Lx1)[j*64 + lane] = sx1[j]; \
    _Pragma("unroll") for (int j = 0; j < 3; ++j) ((float4*)Lx2)[j*64 + lane] = sx2[j]; \
    _Pragma("unroll") for (int j = 0; j < 3; ++j) ((float4*)Lx3)[j*64 + lane] = sx3[j]; \
    _Pragma("unroll") for (int j = 0; j < 7; ++j) ((float4*)Lg )[j*64 + lane] = sg[j];  \
  } while (0)

    // LDS read strides 3 and 7 floats are coprime to 32 banks -> 2-way max (free).
#define COMPUTE(qv1, qv2, qv3, accv) do {                                       \
    _Pragma("unroll") for (int k = 0; k < 4; ++k) {                             \
        const int s = k*64 + lane;                                              \
        const float px  = Lg[7*s + 0];                                          \
        const float py  = Lg[7*s + 1];                                          \
        const float pz  = Lg[7*s + 2];                                          \
        const float qa0 = Lg[7*s + 3];                                          \
        const float qb0 = Lg[7*s + 4];                                          \
        const float qc0 = Lg[7*s + 5];                                          \
        const float qd0 = Lg[7*s + 6];                                          \
        const float dsq = qa0*qa0 + qb0*qb0 + qc0*qc0 + qd0*qd0;                \
        const float inv = fminf(__builtin_amdgcn_rsqf(dsq), 1e12f);             \
        const float qa = qa0*inv, qb = qb0*inv, qc = qc0*inv, qd = qd0*inv;     \
        float dx, dy, dz, dw;                                                   \
        dx = Lx1[3*s+0] - px; dy = Lx1[3*s+1] - py; dz = Lx1[3*s+2] - pz;       \
        const float l1x = __builtin_amdgcn_sqrtf(dx*dx + dy*dy + dz*dz);        \
        dw = qv1[k].x - qa; dx = qv1[k].y - qb; dy = qv1[k].z - qc; dz = qv1[k].w - qd; \
        const float l1q = __builtin_amdgcn_sqrtf(dw*dw + dx*dx + dy*dy + dz*dz);\
        dx = Lx2[3*s+0] - px; dy = Lx2[3*s+1] - py; dz = Lx2[3*s+2] - pz;       \
        const float l2x = __builtin_amdgcn_sqrtf(dx*dx + dy*dy + dz*dz);        \
        dw = qv2[k].x - qa; dx = qv2[k].y - qb; dy = qv2[k].z - qc; dz = qv2[k].w - qd; \
        const float l2q = __builtin_amdgcn_sqrtf(dw*dw + dx*dx + dy*dy + dz*dz);\
        dx = Lx3[3*s+0] - px; dy = Lx3[3*s+1] - py; dz = Lx3[3*s+2] - pz;       \
        const float l3x = __builtin_amdgcn_sqrtf(dx*dx + dy*dy + dz*dz);        \
        dw = qv3[k].x - qa; dx = qv3[k].y - qb; dy = qv3[k].z - qc; dz = qv3[k].w - qd; \
        const float l3q = __builtin_amdgcn_sqrtf(dw*dw + dx*dx + dy*dy + dz*dz);\
        accv += W1_XYZ * (l1x + W1_WPQR * l1q)                                  \
              + W2_XYZ * (l2x + W2_WPQR * l2q)                                  \
              + W3_XYZ * (l3x + W3_WPQR * l3q);                                 \
    } } while (0)

    // ---- issue ALL 50 loads (A then B), pin against sinking ----
    float4 a_x1[3], a_x2[3], a_x3[3], a_g[7], a_q1[4], a_q2[4], a_q3[4];
    ISSUE(a_x1, a_x2, a_x3, a_g, a_q1, a_q2, a_q3, c0);
    float4 b_x1[3], b_x2[3], b_x3[3], b_g[7], b_q1[4], b_q2[4], b_q3[4];
    ISSUE(b_x1, b_x2, b_x3, b_g, b_q1, b_q2, b_q3, c1);
    __builtin_amdgcn_sched_barrier(0);

    float acc = 0.0f;
    // chunk A: ds_write waits only A's loads (counted vmcnt, B stays in flight)
    WRITE_LDS(a_x1, a_x2, a_x3, a_g);
    COMPUTE(a_q1, a_q2, a_q3, acc);
    // chunk B: loads landed under A's compute; same-wave DS ordering protects LDS reuse
    WRITE_LDS(b_x1, b_x2, b_x3, b_g);
    COMPUTE(b_q1, b_q2, b_q3, acc);

    // wave-64 reduction -> one partial per wave
    #pragma unroll
    for (int off = 32; off > 0; off >>= 1)
        acc += __shfl_down(acc, off);
    if (lane == 0) partial[blockIdx.x] = acc;
}

__global__ __launch_bounds__(512) void pose_loss_final(
    const float* __restrict__ partial, float* __restrict__ out, float scale)
{
    const int tid = threadIdx.x;
    const float4 v = ((const float4*)partial)[tid];   // 512 x float4 = 2048 partials
    float acc = (v.x + v.y) + (v.z + v.w);

    #pragma unroll
    for (int off = 32; off > 0; off >>= 1)
        acc += __shfl_down(acc, off);

    __shared__ float smem[8];
    if ((tid & 63) == 0) smem[tid >> 6] = acc;
    __syncthreads();
    if (tid == 0) {
        float s = 0.0f;
        #pragma unroll
        for (int w = 0; w < 8; ++w) s += smem[w];
        out[0] = s * scale;
    }
}

extern "C" void kernel_launch(void* const* d_in, const int* in_sizes, int n_in,
                              void* d_out, int out_size, void* d_ws, size_t ws_size,
                              hipStream_t stream) {
    const float* p1x = (const float*)d_in[0];
    const float* p1q = (const float*)d_in[1];
    const float* p2x = (const float*)d_in[2];
    const float* p2q = (const float*)d_in[3];
    const float* p3x = (const float*)d_in[4];
    const float* p3q = (const float*)d_in[5];
    const float* gt  = (const float*)d_in[6];
    float* out = (float*)d_out;
    float* partial = (float*)d_ws;   // 2048 floats = 8 KiB

    pose_loss_partial<<<NBLOCKS, 64, 0, stream>>>(p1x, p1q, p2x, p2q, p3x, p3q, gt, partial);
    pose_loss_final<<<1, 512, 0, stream>>>(partial, out, 1.0f / (float)B_TOTAL);
}

// Round 8
// 24.447 us; speedup vs baseline: 1.0308x; 1.0308x over previous
//
#include <hip/hip_runtime.h>

// PoseLoss round 8: max-occupancy direct-load hybrid (untested corner).
// R2 (32 waves/CU, shallow MLP after VGPR collapse) = 27.2us; R4/R6/R7
// (8-10 waves/CU, deep MLP) all = 24.5-25.2us. Both far exceed Little's-law
// outstanding-bytes, so test the last orthogonal axis: 16 waves/CU
// (VGPR<=128 tier) x 22 independent loads/thread, NO LDS at all
// (no ds-drain, no LDS occupancy cap, no barrier).
// Per thread (SPT=2): xyz = 3x float2/stream (24B, 8-aligned),
// q = 2x float4/stream, gt = 7x float2 (56B, 8-aligned). Per-wave partials.
// R5 lesson: no device-scope fences/atomics -> keep 2-kernel reduce.

#define W1_XYZ 0.3f
#define W2_XYZ 0.3f
#define W3_XYZ 1.0f
#define W1_WPQR 150.0f
#define W2_WPQR 150.0f
#define W3_WPQR 500.0f

constexpr int B_TOTAL = 1048576;
constexpr int BLOCK   = 256;
constexpr int SPT     = 2;
constexpr int NBLOCKS = B_TOTAL / (BLOCK * SPT);   // 2048
constexpr int NWAVES  = NBLOCKS * (BLOCK / 64);    // 8192

__global__ __launch_bounds__(BLOCK) void pose_loss_partial(
    const float* __restrict__ p1x, const float* __restrict__ p1q,
    const float* __restrict__ p2x, const float* __restrict__ p2q,
    const float* __restrict__ p3x, const float* __restrict__ p3q,
    const float* __restrict__ gt, float* __restrict__ partial)
{
    const int  tid  = threadIdx.x;
    const int  lane = tid & 63;
    const int  wid  = tid >> 6;
    const long t    = (long)blockIdx.x * BLOCK + tid;   // thread -> samples 2t, 2t+1

    // ---- issue all 22 loads as independent named values ----
    const float2* x1p = (const float2*)p1x;   // float2 idx = 3t + {0,1,2}
    const float2* x2p = (const float2*)p2x;
    const float2* x3p = (const float2*)p3x;
    const float2* gp  = (const float2*)gt;    // float2 idx = 7t + {0..6}
    const float4* q1p = (const float4*)p1q;   // float4 idx = 2t + {0,1}
    const float4* q2p = (const float4*)p2q;
    const float4* q3p = (const float4*)p3q;

    const float2 g0 = gp[7*t + 0];
    const float2 g1 = gp[7*t + 1];
    const float2 g2 = gp[7*t + 2];
    const float2 g3 = gp[7*t + 3];
    const float2 g4 = gp[7*t + 4];
    const float2 g5 = gp[7*t + 5];
    const float2 g6 = gp[7*t + 6];

    const float2 a0 = x1p[3*t + 0];
    const float2 a1 = x1p[3*t + 1];
    const float2 a2 = x1p[3*t + 2];
    const float2 b0 = x2p[3*t + 0];
    const float2 b1 = x2p[3*t + 1];
    const float2 b2 = x2p[3*t + 2];
    const float2 c0 = x3p[3*t + 0];
    const float2 c1 = x3p[3*t + 1];
    const float2 c2 = x3p[3*t + 2];

    const float4 qA0 = q1p[2*t + 0];
    const float4 qA1 = q1p[2*t + 1];
    const float4 qB0 = q2p[2*t + 0];
    const float4 qB1 = q2p[2*t + 1];
    const float4 qC0 = q3p[2*t + 0];
    const float4 qC1 = q3p[2*t + 1];

    __builtin_amdgcn_sched_barrier(0);

    float acc = 0.0f;

    // ---- sample 0: gt = (g0.x g0.y g1.x | g1.y g2.x g2.y g3.x) ----
    {
        const float px = g0.x, py = g0.y, pz = g1.x;
        const float qa0 = g1.y, qb0 = g2.x, qc0 = g2.y, qd0 = g3.x;
        const float dsq = qa0*qa0 + qb0*qb0 + qc0*qc0 + qd0*qd0;
        const float inv = fminf(__builtin_amdgcn_rsqf(dsq), 1e12f);   // == 1/max(sqrt,1e-12)
        const float qa = qa0*inv, qb = qb0*inv, qc = qc0*inv, qd = qd0*inv;
        float dx, dy, dz, dw;

        dx = a0.x - px; dy = a0.y - py; dz = a1.x - pz;
        const float l1x = __builtin_amdgcn_sqrtf(dx*dx + dy*dy + dz*dz);
        dw = qA0.x - qa; dx = qA0.y - qb; dy = qA0.z - qc; dz = qA0.w - qd;
        const float l1q = __builtin_amdgcn_sqrtf(dw*dw + dx*dx + dy*dy + dz*dz);

        dx = b0.x - px; dy = b0.y - py; dz = b1.x - pz;
        const float l2x = __builtin_amdgcn_sqrtf(dx*dx + dy*dy + dz*dz);
        dw = qB0.x - qa; dx = qB0.y - qb; dy = qB0.z - qc; dz = qB0.w - qd;
        const float l2q = __builtin_amdgcn_sqrtf(dw*dw + dx*dx + dy*dy + dz*dz);

        dx = c0.x - px; dy = c0.y - py; dz = c1.x - pz;
        const float l3x = __builtin_amdgcn_sqrtf(dx*dx + dy*dy + dz*dz);
        dw = qC0.x - qa; dx = qC0.y - qb; dy = qC0.z - qc; dz = qC0.w - qd;
        const float l3q = __builtin_amdgcn_sqrtf(dw*dw + dx*dx + dy*dy + dz*dz);

        acc += W1_XYZ * (l1x + W1_WPQR * l1q)
             + W2_XYZ * (l2x + W2_WPQR * l2q)
             + W3_XYZ * (l3x + W3_WPQR * l3q);
    }

    // ---- sample 1: gt = (g3.y g4.x g4.y | g5.x g5.y g6.x g6.y) ----
    {
        const float px = g3.y, py = g4.x, pz = g4.y;
        const float qa0 = g5.x, qb0 = g5.y, qc0 = g6.x, qd0 = g6.y;
        const float dsq = qa0*qa0 + qb0*qb0 + qc0*qc0 + qd0*qd0;
        const float inv = fminf(__builtin_amdgcn_rsqf(dsq), 1e12f);
        const float qa = qa0*inv, qb = qb0*inv, qc = qc0*inv, qd = qd0*inv;
        float dx, dy, dz, dw;

        dx = a1.y - px; dy = a2.x - py; dz = a2.y - pz;
        const float l1x = __builtin_amdgcn_sqrtf(dx*dx + dy*dy + dz*dz);
        dw = qA1.x - qa; dx = qA1.y - qb; dy = qA1.z - qc; dz = qA1.w - qd;
        const float l1q = __builtin_amdgcn_sqrtf(dw*dw + dx*dx + dy*dy + dz*dz);

        dx = b1.y - px; dy = b2.x - py; dz = b2.y - pz;
        const float l2x = __builtin_amdgcn_sqrtf(dx*dx + dy*dy + dz*dz);
        dw = qB1.x - qa; dx = qB1.y - qb; dy = qB1.z - qc; dz = qB1.w - qd;
        const float l2q = __builtin_amdgcn_sqrtf(dw*dw + dx*dx + dy*dy + dz*dz);

        dx = c1.y - px; dy = c2.x - py; dz = c2.y - pz;
        const float l3x = __builtin_amdgcn_sqrtf(dx*dx + dy*dy + dz*dz);
        dw = qC1.x - qa; dx = qC1.y - qb; dy = qC1.z - qc; dz = qC1.w - qd;
        const float l3q = __builtin_amdgcn_sqrtf(dw*dw + dx*dx + dy*dy + dz*dz);

        acc += W1_XYZ * (l1x + W1_WPQR * l1q)
             + W2_XYZ * (l2x + W2_WPQR * l2q)
             + W3_XYZ * (l3x + W3_WPQR * l3q);
    }

    // wave-64 reduction -> one partial per WAVE (no LDS, no barrier)
    #pragma unroll
    for (int off = 32; off > 0; off >>= 1)
        acc += __shfl_down(acc, off);
    if (lane == 0) partial[(long)blockIdx.x * (BLOCK / 64) + wid] = acc;
}

__global__ __launch_bounds__(256) void pose_loss_final(
    const float* __restrict__ partial, float* __restrict__ out, float scale)
{
    const int tid = threadIdx.x;
    float acc = 0.0f;
    #pragma unroll
    for (int j = 0; j < NWAVES / 4 / 256; ++j) {          // 8 float4 per thread
        const float4 v = ((const float4*)partial)[j * 256 + tid];
        acc += (v.x + v.y) + (v.z + v.w);
    }

    #pragma unroll
    for (int off = 32; off > 0; off >>= 1)
        acc += __shfl_down(acc, off);

    __shared__ float smem[4];
    if ((tid & 63) == 0) smem[tid >> 6] = acc;
    __syncthreads();
    if (tid == 0) {
        float s = 0.0f;
        #pragma unroll
        for (int w = 0; w < 4; ++w) s += smem[w];
        out[0] = s * scale;
    }
}

extern "C" void kernel_launch(void* const* d_in, const int* in_sizes, int n_in,
                              void* d_out, int out_size, void* d_ws, size_t ws_size,
                              hipStream_t stream) {
    const float* p1x = (const float*)d_in[0];
    const float* p1q = (const float*)d_in[1];
    const float* p2x = (const float*)d_in[2];
    const float* p2q = (const float*)d_in[3];
    const float* p3x = (const float*)d_in[4];
    const float* p3q = (const float*)d_in[5];
    const float* gt  = (const float*)d_in[6];
    float* out = (float*)d_out;
    float* partial = (float*)d_ws;   // NWAVES floats = 32 KiB

    pose_loss_partial<<<NBLOCKS, BLOCK, 0, stream>>>(p1x, p1q, p2x, p2q, p3x, p3q, gt, partial);
    pose_loss_final<<<1, 256, 0, stream>>>(partial, out, 1.0f / (float)B_TOTAL);
}